// Round 3
// baseline (2248.635 us; speedup 1.0000x reference)
//
#include <hip/hip_runtime.h>
#include <math.h>

// Problem constants
#define BB 64
#define NN 100
#define HH 128
#define T3 384

// Output layout (floats, concatenated in return order)
#define O0 0            // sample_logprob [64,99]
#define O1 6336         // sample_distance [64,1]
#define O2 6400         // greedy_distance [64,1]
#define O3 6464         // predict_matrix [64,100,100,2]
#define O4 1286464      // greedy_solution_matrix [64,100,100]

#define TINYF 1.17549435e-38f
#define SCALEF 0.08838834764831845f

// ---------------- threefry2x32 (exact JAX implementation) ----------------
__device__ __forceinline__ unsigned rotl32(unsigned x, int d) {
    return (x << d) | (x >> (32 - d));
}

__device__ __forceinline__ void tf2x32(unsigned ks0, unsigned ks1,
                                       unsigned x0, unsigned x1,
                                       unsigned& o0, unsigned& o1) {
    unsigned ks2 = ks0 ^ ks1 ^ 0x1BD11BDAu;
    x0 += ks0; x1 += ks1;
    x0 += x1; x1 = rotl32(x1, 13); x1 ^= x0;
    x0 += x1; x1 = rotl32(x1, 15); x1 ^= x0;
    x0 += x1; x1 = rotl32(x1, 26); x1 ^= x0;
    x0 += x1; x1 = rotl32(x1, 6);  x1 ^= x0;
    x0 += ks1; x1 += ks2 + 1u;
    x0 += x1; x1 = rotl32(x1, 17); x1 ^= x0;
    x0 += x1; x1 = rotl32(x1, 29); x1 ^= x0;
    x0 += x1; x1 = rotl32(x1, 16); x1 ^= x0;
    x0 += x1; x1 = rotl32(x1, 24); x1 ^= x0;
    x0 += ks2; x1 += ks0 + 2u;
    x0 += x1; x1 = rotl32(x1, 13); x1 ^= x0;
    x0 += x1; x1 = rotl32(x1, 15); x1 ^= x0;
    x0 += x1; x1 = rotl32(x1, 26); x1 ^= x0;
    x0 += x1; x1 = rotl32(x1, 6);  x1 ^= x0;
    x0 += ks0; x1 += ks1 + 3u;
    x0 += x1; x1 = rotl32(x1, 17); x1 ^= x0;
    x0 += x1; x1 = rotl32(x1, 29); x1 ^= x0;
    x0 += x1; x1 = rotl32(x1, 16); x1 ^= x0;
    x0 += x1; x1 = rotl32(x1, 24); x1 ^= x0;
    x0 += ks1; x1 += ks2 + 4u;
    x0 += x1; x1 = rotl32(x1, 13); x1 ^= x0;
    x0 += x1; x1 = rotl32(x1, 15); x1 ^= x0;
    x0 += x1; x1 = rotl32(x1, 26); x1 ^= x0;
    x0 += x1; x1 = rotl32(x1, 6);  x1 ^= x0;
    x0 += ks2; x1 += ks0 + 5u;
    o0 = x0; o1 = x1;
}

__device__ __forceinline__ float gumbel_f(unsigned k0, unsigned k1, unsigned f) {
    unsigned o0, o1;
    tf2x32(k0, k1, 0u, f, o0, o1);
    unsigned bits = o0 ^ o1;
    float u01 = __uint_as_float((bits >> 9) | 0x3F800000u) - 1.0f;
    float u = fmaxf(TINYF, u01 * (1.0f - TINYF) + TINYF);
    return -logf(-logf(u));
}

// ---------------- encoder kernels ----------------

__global__ void k_embed(const float* __restrict__ node, const float* __restrict__ demand,
                        const float* __restrict__ Wn0, const float* __restrict__ bn0,
                        float* __restrict__ h) {
    int idx = blockIdx.x * 256 + threadIdx.x;
    if (idx >= BB * NN * HH) return;
    int r = idx >> 7, c = idx & 127;
    float v = node[r * 2] * Wn0[c] + node[r * 2 + 1] * Wn0[128 + c]
            + demand[r] * Wn0[256 + c] + bn0[c];
    h[idx] = fmaxf(v, 0.0f);
}

__global__ void k_adj(const float* __restrict__ dis, float* __restrict__ A) {
    int row = blockIdx.x;
    const float* d = dis + row * NN;
    int l = threadIdx.x;
    float v0 = (l < NN) ? -d[l] : -__builtin_inff();
    float v1 = (l + 64 < NN) ? -d[l + 64] : -__builtin_inff();
    float m = fmaxf(v0, v1);
    for (int off = 32; off > 0; off >>= 1) m = fmaxf(m, __shfl_xor(m, off));
    float e0 = (l < NN) ? expf(v0 - m) : 0.0f;
    float e1 = (l + 64 < NN) ? expf(v1 - m) : 0.0f;
    float s = e0 + e1;
    for (int off = 32; off > 0; off >>= 1) s += __shfl_xor(s, off);
    float inv = 1.0f / s;
    if (l < NN) A[row * NN + l] = e0 * inv;
    if (l + 64 < NN) A[row * NN + l + 64] = e1 * inv;
}

// out[6400x128] = h[6400x128] @ W[128x128]
__global__ void k_hw(const float* __restrict__ h, const float* __restrict__ W,
                     float* __restrict__ out) {
    __shared__ float hs[8 * 128];
    int block_row = blockIdx.x * 8;
    int tid = threadIdx.x;
    int col = tid & 127;
    int rg = tid >> 7;
    for (int i = tid; i < 8 * 128; i += 256) hs[i] = h[block_row * 128 + i];
    __syncthreads();
    float acc[4] = {0.f, 0.f, 0.f, 0.f};
    for (int k = 0; k < 128; k++) {
        float w = W[k * 128 + col];
#pragma unroll
        for (int r = 0; r < 4; r++) acc[r] += hs[(rg + 2 * r) * 128 + k] * w;
    }
#pragma unroll
    for (int r = 0; r < 4; r++)
        out[(block_row + rg + 2 * r) * 128 + col] = acc[r];
}

// out[6400x384] = h[6400x128] @ W[128x384] + bias[384]
__global__ void k_mm384(const float* __restrict__ h, const float* __restrict__ W,
                        const float* __restrict__ bias, float* __restrict__ out) {
    __shared__ float hs[8 * 128];
    int block_row = blockIdx.x * 8;
    int tid = threadIdx.x;
    int col = blockIdx.y * 128 + (tid & 127);
    int rg = tid >> 7;
    for (int i = tid; i < 8 * 128; i += 256) hs[i] = h[block_row * 128 + i];
    __syncthreads();
    float acc[4] = {0.f, 0.f, 0.f, 0.f};
    for (int k = 0; k < 128; k++) {
        float w = W[k * 384 + col];
#pragma unroll
        for (int r = 0; r < 4; r++) acc[r] += hs[(rg + 2 * r) * 128 + k] * w;
    }
    float b = bias[col];
#pragma unroll
    for (int r = 0; r < 4; r++)
        out[(block_row + rg + 2 * r) * 384 + col] = acc[r] + b;
}

__global__ void k_transpose128(const float* __restrict__ Wq, float* __restrict__ WqT) {
    int i = blockIdx.x * 256 + threadIdx.x;
    if (i >= 128 * 128) return;
    int k = i >> 7, c = i & 127;
    WqT[k * 128 + c] = Wq[c * 128 + k];
}

__global__ void k_agg(const float* __restrict__ h, const float* __restrict__ Ws,
                      const float* __restrict__ A, const float* __restrict__ hw,
                      float* __restrict__ out) {
    __shared__ float hs[4 * 128];
    __shared__ float As[4 * 100];
    int b = blockIdx.x / 25;
    int i0 = (blockIdx.x % 25) * 4;
    int tid = threadIdx.x;
    int col = tid & 127;
    int rg = tid >> 7;
    int rowbase = b * NN + i0;
    for (int idx = tid; idx < 4 * 128; idx += 256) hs[idx] = h[rowbase * 128 + idx];
    for (int idx = tid; idx < 4 * 100; idx += 256) As[idx] = A[rowbase * 100 + idx];
    __syncthreads();
    float acc0 = 0.f, acc1 = 0.f;
    for (int k = 0; k < 128; k++) {
        float w = Ws[k * 128 + col];
        acc0 += hs[rg * 128 + k] * w;
        acc1 += hs[(rg + 2) * 128 + k] * w;
    }
    const float* hwb = hw + b * NN * 128;
    for (int j = 0; j < NN; j++) {
        float v = hwb[j * 128 + col];
        acc0 += As[rg * 100 + j] * v;
        acc1 += As[(rg + 2) * 100 + j] * v;
    }
    out[(rowbase + rg) * 128 + col]     = fmaxf(acc0, 0.0f);
    out[(rowbase + rg + 2) * 128 + col] = fmaxf(acc1, 0.0f);
}

__global__ void k_predict(const float* __restrict__ dis, const float* __restrict__ We,
                          const float* __restrict__ be, const float* __restrict__ Wc,
                          const float* __restrict__ bc, float* __restrict__ out3) {
    __shared__ float sWe[128], sbe[128], sc0[128], sc1[128];
    int tid = threadIdx.x;
    if (tid < 128) {
        sWe[tid] = We[tid];
        sbe[tid] = be[tid];
        sc0[tid] = Wc[tid * 2];
        sc1[tid] = Wc[tid * 2 + 1];
    }
    __syncthreads();
    float b0 = bc[0], b1 = bc[1];
    for (int pos = blockIdx.x * 256 + tid; pos < BB * NN * NN; pos += gridDim.x * 256) {
        float d = dis[pos];
        float a0 = b0, a1 = b1;
        for (int k = 0; k < 128; k++) {
            float e = fmaxf(d * sWe[k] + sbe[k], 0.0f);
            a0 += e * sc0[k];
            a1 += e * sc1[k];
        }
        float m = fmaxf(a0, a1);
        float p0 = expf(a0 - m), p1 = expf(a1 - m);
        float inv = 1.0f / (p0 + p1);
        out3[pos * 2]     = p0 * inv;
        out3[pos * 2 + 1] = p1 * inv;
    }
}

__global__ void k_zero(float* __restrict__ p, int n) {
    int i = blockIdx.x * 256 + threadIdx.x;
    if (i < n) p[i] = 0.0f;
}

// ---------------- decoder v3: 64 blocks, both modes per block, reg-blocked ----------------
// hrep layout: hrep[(rep*2 + m)*140 + k], 8 replicas, bank-staggered by 280*4B per rep.
__global__ __launch_bounds__(768, 3) void k_decode3(
    const float* __restrict__ P0,       // [6400, 384]  x@Wih0 + bih0
    const float* __restrict__ Z,        // [6400, 128]  x@Wq^T
    const float* __restrict__ dis,
    const float* __restrict__ Wih,      // [2,128,384]
    const float* __restrict__ Whh,      // [2,128,384]
    const float* __restrict__ bih,     // unused (P0 precomputed) except layer1
    const float* __restrict__ bhh,
    float* __restrict__ out) {
    __shared__ float Zs[NN * 132];           // 52.8 KB, float4-aligned rows
    __shared__ float hrep0[8 * 2 * 140];     // 8.96 KB
    __shared__ float hrep1[8 * 2 * 140];     // 8.96 KB
    __shared__ float gi0s[2 * 384];          // 3 KB
    __shared__ float pgA[2 * 4 * 2 * 392];   // 25 KB  [unit][ks][m][j] padded
    __shared__ float pgC[8 * 2 * 392];       // 25 KB  [ks][m][j] padded
    __shared__ float sbhh0[T3], sbih1[T3], sbhh1[T3];
    __shared__ float pl[2 * 4 * 100];        // [m][p][n]
    __shared__ float gum[128];
    __shared__ int s_ind2[2];

    const int tid = threadIdx.x;
    const int b = blockIdx.x;

    // ---- static staging ----
    for (int i4 = tid; i4 < NN * 32; i4 += 768) {
        int r = i4 >> 5, c4 = (i4 & 31) * 4;
        *(float4*)&Zs[r * 132 + c4] = *(const float4*)&Z[(b * NN + r) * 128 + c4];
    }
    if (tid < T3) {
        sbhh0[tid] = bhh[tid];
        sbih1[tid] = bih[T3 + tid];
        sbhh1[tid] = bhh[T3 + tid];
    }
    if (tid < 256) {
        int m = tid >> 7, i = tid & 127;
#pragma unroll
        for (int rep = 0; rep < 8; rep++) {
            hrep0[(rep * 2 + m) * 140 + i] = 0.0f;
            hrep1[(rep * 2 + m) * 140 + i] = 0.0f;
        }
    }
    if (tid == 0) { s_ind2[0] = 0; s_ind2[1] = 0; }

    unsigned kk0, kk1;
    tf2x32(0u, 42u, 0u, 0u, kk0, kk1);   // k1 of split(key(42))

    int lastm = 0;       // meaningful in waves 0/1 (selection) only
    float dist = 0.0f;
    __syncthreads();

    for (int t = 0; t < NN - 1; t++) {
        // ======== phase A: gh0 (unit0) & gh1 (unit1) partials; waves 6-11: gi0 + RNG ========
        if (tid < 384) {
            const int unit = tid / 192;                 // 0: Whh0*h0, 1: Whh1*h1
            const int r = tid % 192;
            const int jg = r >> 2, ks = r & 3;
            const int j0 = jg * 8, k0 = ks * 32;
            const float* __restrict__ W = Whh + unit * 128 * T3;
            const float* __restrict__ hsrc = (unit == 0) ? hrep0 : hrep1;
            float a[2][8];
#pragma unroll
            for (int m = 0; m < 2; m++)
#pragma unroll
                for (int j = 0; j < 8; j++) a[m][j] = 0.0f;
#pragma unroll
            for (int half = 0; half < 2; half++) {
                const int kb = k0 + half * 16;
                float hh0[16], hh1[16];
#pragma unroll
                for (int q = 0; q < 4; q++) {
                    float4 v0 = *(const float4*)&hsrc[(ks * 2 + 0) * 140 + kb + 4 * q];
                    float4 v1 = *(const float4*)&hsrc[(ks * 2 + 1) * 140 + kb + 4 * q];
                    hh0[4*q] = v0.x; hh0[4*q+1] = v0.y; hh0[4*q+2] = v0.z; hh0[4*q+3] = v0.w;
                    hh1[4*q] = v1.x; hh1[4*q+1] = v1.y; hh1[4*q+2] = v1.z; hh1[4*q+3] = v1.w;
                }
#pragma unroll
                for (int kk = 0; kk < 16; kk++) {
                    float4 w0 = *(const float4*)&W[(kb + kk) * T3 + j0];
                    float4 w1 = *(const float4*)&W[(kb + kk) * T3 + j0 + 4];
                    float x0 = hh0[kk], x1 = hh1[kk];
                    a[0][0] += w0.x * x0; a[0][1] += w0.y * x0;
                    a[0][2] += w0.z * x0; a[0][3] += w0.w * x0;
                    a[0][4] += w1.x * x0; a[0][5] += w1.y * x0;
                    a[0][6] += w1.z * x0; a[0][7] += w1.w * x0;
                    a[1][0] += w0.x * x1; a[1][1] += w0.y * x1;
                    a[1][2] += w0.z * x1; a[1][3] += w0.w * x1;
                    a[1][4] += w1.x * x1; a[1][5] += w1.y * x1;
                    a[1][6] += w1.z * x1; a[1][7] += w1.w * x1;
                }
            }
#pragma unroll
            for (int m = 0; m < 2; m++) {
                int base = ((unit * 4 + ks) * 2 + m) * 392 + j0;
                float4 o;
                o.x = a[m][0]; o.y = a[m][1]; o.z = a[m][2]; o.w = a[m][3];
                *(float4*)&pgA[base] = o;
                o.x = a[m][4]; o.y = a[m][5]; o.z = a[m][6]; o.w = a[m][7];
                *(float4*)&pgA[base + 4] = o;
            }
        } else {
            int u = tid - 384;                          // 0..383
            int m = u / 192, j2 = (u % 192) * 2;
            int lastv = s_ind2[m];
            float2 g2 = *(const float2*)&P0[(size_t)(b * NN + lastv) * T3 + j2];
            gi0s[m * 384 + j2] = g2.x;
            gi0s[m * 384 + j2 + 1] = g2.y;
            if (tid < 448) {                            // wave 6: RNG chain + gumbel table
                unsigned sk0, sk1, nk0, nk1;
                tf2x32(kk0, kk1, 0u, 1u, sk0, sk1);
                tf2x32(kk0, kk1, 0u, 0u, nk0, nk1);
                kk0 = nk0; kk1 = nk1;
                int lane = tid & 63;
                gum[lane] = gumbel_f(sk0, sk1, (unsigned)(b * NN + lane));
                if (lane + 64 < NN)
                    gum[lane + 64] = gumbel_f(sk0, sk1, (unsigned)(b * NN + lane + 64));
            }
        }
        __syncthreads();

        // ======== phase B: h0 update ========
        if (tid < 256) {
            int m = tid >> 7, i = tid & 127;
            float ghr = 0.f, ghz = 0.f, ghn = 0.f;
#pragma unroll
            for (int ks = 0; ks < 4; ks++) {
                int pb = (ks * 2 + m) * 392;
                ghr += pgA[pb + i];
                ghz += pgA[pb + i + 128];
                ghn += pgA[pb + i + 256];
            }
            ghr += sbhh0[i]; ghz += sbhh0[i + 128]; ghn += sbhh0[i + 256];
            float rr = 1.0f / (1.0f + expf(-(gi0s[m * 384 + i] + ghr)));
            float zz = 1.0f / (1.0f + expf(-(gi0s[m * 384 + i + 128] + ghz)));
            float nn = tanhf(gi0s[m * 384 + i + 256] + rr * ghn);
            float hold = hrep0[m * 140 + i];
            float hnew = (1.0f - zz) * nn + zz * hold;
#pragma unroll
            for (int rep = 0; rep < 8; rep++) hrep0[(rep * 2 + m) * 140 + i] = hnew;
        }
        __syncthreads();

        // ======== phase C: gi1 partials (all 768 threads) ========
        {
            const int jg = tid >> 3, ks = tid & 7;
            const int j0 = jg * 4, k0 = ks * 16;
            const float* __restrict__ W = Wih + 128 * T3;   // Wih1
            float hh0[16], hh1[16];
#pragma unroll
            for (int q = 0; q < 4; q++) {
                float4 v0 = *(const float4*)&hrep0[(ks * 2 + 0) * 140 + k0 + 4 * q];
                float4 v1 = *(const float4*)&hrep0[(ks * 2 + 1) * 140 + k0 + 4 * q];
                hh0[4*q] = v0.x; hh0[4*q+1] = v0.y; hh0[4*q+2] = v0.z; hh0[4*q+3] = v0.w;
                hh1[4*q] = v1.x; hh1[4*q+1] = v1.y; hh1[4*q+2] = v1.z; hh1[4*q+3] = v1.w;
            }
            float a0[4] = {0.f,0.f,0.f,0.f}, a1[4] = {0.f,0.f,0.f,0.f};
#pragma unroll
            for (int kk = 0; kk < 16; kk++) {
                float4 w = *(const float4*)&W[(k0 + kk) * T3 + j0];
                a0[0] += w.x * hh0[kk]; a0[1] += w.y * hh0[kk];
                a0[2] += w.z * hh0[kk]; a0[3] += w.w * hh0[kk];
                a1[0] += w.x * hh1[kk]; a1[1] += w.y * hh1[kk];
                a1[2] += w.z * hh1[kk]; a1[3] += w.w * hh1[kk];
            }
            float4 o;
            o.x = a0[0]; o.y = a0[1]; o.z = a0[2]; o.w = a0[3];
            *(float4*)&pgC[(ks * 2 + 0) * 392 + j0] = o;
            o.x = a1[0]; o.y = a1[1]; o.z = a1[2]; o.w = a1[3];
            *(float4*)&pgC[(ks * 2 + 1) * 392 + j0] = o;
        }
        __syncthreads();

        // ======== phase D: h1 update ========
        if (tid < 256) {
            int m = tid >> 7, i = tid & 127;
            float gir = 0.f, giz = 0.f, gin = 0.f;
#pragma unroll
            for (int ks = 0; ks < 8; ks++) {
                int pb = (ks * 2 + m) * 392;
                gir += pgC[pb + i];
                giz += pgC[pb + i + 128];
                gin += pgC[pb + i + 256];
            }
            gir += sbih1[i]; giz += sbih1[i + 128]; gin += sbih1[i + 256];
            float ghr = 0.f, ghz = 0.f, ghn = 0.f;
#pragma unroll
            for (int ks = 0; ks < 4; ks++) {
                int pb = ((4 + ks) * 2 + m) * 392;
                ghr += pgA[pb + i];
                ghz += pgA[pb + i + 128];
                ghn += pgA[pb + i + 256];
            }
            ghr += sbhh1[i]; ghz += sbhh1[i + 128]; ghn += sbhh1[i + 256];
            float rr = 1.0f / (1.0f + expf(-(gir + ghr)));
            float zz = 1.0f / (1.0f + expf(-(giz + ghz)));
            float nn = tanhf(gin + rr * ghn);
            float hold = hrep1[m * 140 + i];
            float hnew = (1.0f - zz) * nn + zz * hold;
#pragma unroll
            for (int rep = 0; rep < 8; rep++) hrep1[(rep * 2 + m) * 140 + i] = hnew;
        }
        __syncthreads();

        // ======== phase E: logits partials [m][p][n] ========
        if (tid < 400) {
            int p = tid / 100, n = tid % 100;
            int k0 = p * 32;
            float a0 = 0.f, a1 = 0.f;
#pragma unroll
            for (int q = 0; q < 8; q++) {
                float4 zz = *(const float4*)&Zs[n * 132 + k0 + 4 * q];
                float4 h0v = *(const float4*)&hrep1[(p * 2 + 0) * 140 + k0 + 4 * q];
                float4 h1v = *(const float4*)&hrep1[(p * 2 + 1) * 140 + k0 + 4 * q];
                a0 += h0v.x * zz.x; a0 += h0v.y * zz.y; a0 += h0v.z * zz.z; a0 += h0v.w * zz.w;
                a1 += h1v.x * zz.x; a1 += h1v.y * zz.y; a1 += h1v.z * zz.z; a1 += h1v.w * zz.w;
            }
            pl[(0 * 4 + p) * 100 + n] = a0;
            pl[(1 * 4 + p) * 100 + n] = a1;
        }
        __syncthreads();

        // ======== phase F: softmax stats + selection (wave0: sample, wave1: greedy) ========
        if (tid < 128) {
            const int m = tid >> 6, lane = tid & 63;
            float v0, v1 = -__builtin_inff();
            {
                int n = lane;
                v0 = (pl[(m * 4 + 0) * 100 + n] + pl[(m * 4 + 1) * 100 + n]
                    + pl[(m * 4 + 2) * 100 + n] + pl[(m * 4 + 3) * 100 + n]) * SCALEF;
            }
            if (lane + 64 < NN) {
                int n = lane + 64;
                v1 = (pl[(m * 4 + 0) * 100 + n] + pl[(m * 4 + 1) * 100 + n]
                    + pl[(m * 4 + 2) * 100 + n] + pl[(m * 4 + 3) * 100 + n]) * SCALEF;
            }
            float mx = fmaxf(v0, v1);
            for (int off = 32; off > 0; off >>= 1) mx = fmaxf(mx, __shfl_xor(mx, off));
            float e = expf(v0 - mx) + ((lane + 64 < NN) ? expf(v1 - mx) : 0.0f);
            for (int off = 32; off > 0; off >>= 1) e += __shfl_xor(e, off);
            float a0 = v0, a1 = v1;
            if (m == 0) {
                a0 += gum[lane];
                if (lane + 64 < NN) a1 += gum[lane + 64];
            }
            float bv; int bi;
            if (a1 > a0) { bv = a1; bi = lane + 64; } else { bv = a0; bi = lane; }
            for (int off = 32; off > 0; off >>= 1) {
                float ov = __shfl_xor(bv, off);
                int   oi = __shfl_xor(bi, off);
                if (ov > bv || (ov == bv && oi < bi)) { bv = ov; bi = oi; }
            }
            int ind = bi;
            float la = __shfl(v0, ind & 63);
            float lb = __shfl(v1, ind & 63);
            float lv = (ind < 64) ? la : lb;
            if (lane == 0) {
                if (m == 0) out[O0 + b * (NN - 1) + t] = lv - mx - logf(e);
                else        out[O4 + (size_t)b * NN * NN + lastm * NN + ind] = 1.0f;
                s_ind2[m] = ind;
            }
            dist += dis[b * NN * NN + lastm * NN + ind];
            lastm = ind;
        }
        __syncthreads();
    }

    if (tid == 0)  out[O1 + b] = dist;
    if (tid == 64) out[O2 + b] = dist;
}

// ---------------- fallback decoder (round-2, needs only small ws) ----------------
__global__ __launch_bounds__(768) void k_decode2(
    const float* __restrict__ P0, const float* __restrict__ Z,
    const float* __restrict__ dis,
    const float* __restrict__ Wih, const float* __restrict__ Whh,
    const float* __restrict__ bih, const float* __restrict__ bhh,
    float* __restrict__ out) {
    __shared__ float Zs[NN * 129];
    __shared__ float h0s[128], h1s[128];
    __shared__ float gi0s[T3];
    __shared__ float pg0[2 * T3];
    __shared__ float gi1s[T3], gh1s[T3];
    __shared__ float sbhh0[T3], sbih1[T3], sbhh1[T3];
    __shared__ float plx[4 * NN];
    __shared__ float logits[NN];
    __shared__ float s_m, s_s;
    __shared__ int s_ind;

    const int tid = threadIdx.x;
    const int b = blockIdx.x >> 1;
    const int greedy = blockIdx.x & 1;

    const float* Whh0 = Whh;
    const float* Wih1 = Wih + 128 * T3;
    const float* Whh1 = Whh + 128 * T3;

    for (int idx = tid; idx < NN * 128; idx += 768) {
        int r = idx >> 7, c = idx & 127;
        Zs[r * 129 + c] = Z[(b * NN + r) * 128 + c];
    }
    if (tid < T3) {
        sbhh0[tid] = bhh[tid];
        sbih1[tid] = bih[T3 + tid];
        sbhh1[tid] = bhh[T3 + tid];
    }
    if (tid < 128) { h0s[tid] = 0.0f; h1s[tid] = 0.0f; }

    unsigned kk0, kk1;
    tf2x32(0u, 42u, 0u, 0u, kk0, kk1);

    int last = 0;
    float dist = 0.0f;
    __syncthreads();

    for (int t = 0; t < NN - 1; t++) {
        unsigned sk0, sk1, nk0, nk1;
        tf2x32(kk0, kk1, 0u, 1u, sk0, sk1);
        tf2x32(kk0, kk1, 0u, 0u, nk0, nk1);
        kk0 = nk0; kk1 = nk1;

        {
            const float* P0row = P0 + (size_t)(b * NN + last) * T3;
            if (tid < T3) {
                int j = tid;
                float acc = 0.0f;
                for (int k = 0; k < 64; k++) acc += h0s[k] * Whh0[k * T3 + j];
                pg0[j] = acc;
                gi0s[j] = P0row[j];
            } else {
                int j = tid - T3;
                float acc = 0.0f;
                for (int k = 64; k < 128; k++) acc += h0s[k] * Whh0[k * T3 + j];
                pg0[T3 + j] = acc;
            }
        }
        __syncthreads();
        if (tid < 128) {
            float ghr = pg0[tid] + pg0[T3 + tid] + sbhh0[tid];
            float ghz = pg0[tid + 128] + pg0[T3 + tid + 128] + sbhh0[tid + 128];
            float ghn = pg0[tid + 256] + pg0[T3 + tid + 256] + sbhh0[tid + 256];
            float r = 1.0f / (1.0f + expf(-(gi0s[tid] + ghr)));
            float z = 1.0f / (1.0f + expf(-(gi0s[tid + 128] + ghz)));
            float n = tanhf(gi0s[tid + 256] + r * ghn);
            h0s[tid] = (1.0f - z) * n + z * h0s[tid];
        }
        __syncthreads();
        if (tid < T3) {
            int j = tid;
            float acc = sbih1[j];
            for (int k = 0; k < 128; k++) acc += h0s[k] * Wih1[k * T3 + j];
            gi1s[j] = acc;
        } else {
            int j = tid - T3;
            float acc = sbhh1[j];
            for (int k = 0; k < 128; k++) acc += h1s[k] * Whh1[k * T3 + j];
            gh1s[j] = acc;
        }
        __syncthreads();
        if (tid < 128) {
            float r = 1.0f / (1.0f + expf(-(gi1s[tid] + gh1s[tid])));
            float z = 1.0f / (1.0f + expf(-(gi1s[tid + 128] + gh1s[tid + 128])));
            float n = tanhf(gi1s[tid + 256] + r * gh1s[tid + 256]);
            h1s[tid] = (1.0f - z) * n + z * h1s[tid];
        }
        __syncthreads();
        if (tid < 400) {
            int n = tid % 100, p = tid / 100;
            int k0 = p * 32;
            float acc = 0.0f;
            for (int kk = 0; kk < 32; kk++) acc += h1s[k0 + kk] * Zs[n * 129 + k0 + kk];
            plx[p * 100 + n] = acc;
        }
        __syncthreads();
        if (tid < 64) {
            float v0 = -__builtin_inff(), v1 = -__builtin_inff();
            {
                int n = tid;
                v0 = (plx[n] + plx[100 + n] + plx[200 + n] + plx[300 + n]) * SCALEF;
                logits[n] = v0;
            }
            if (tid + 64 < NN) {
                int n = tid + 64;
                v1 = (plx[n] + plx[100 + n] + plx[200 + n] + plx[300 + n]) * SCALEF;
                logits[n] = v1;
            }
            float m = fmaxf(v0, v1);
            for (int off = 32; off > 0; off >>= 1) m = fmaxf(m, __shfl_xor(m, off));
            float e = expf(v0 - m) + ((tid + 64 < NN) ? expf(v1 - m) : 0.0f);
            for (int off = 32; off > 0; off >>= 1) e += __shfl_xor(e, off);
            float a0 = v0, a1 = v1;
            if (!greedy) {
                a0 = v0 + gumbel_f(sk0, sk1, (unsigned)(b * NN + tid));
                if (tid + 64 < NN) a1 = v1 + gumbel_f(sk0, sk1, (unsigned)(b * NN + tid + 64));
            }
            float bv; int bi;
            if (a1 > a0) { bv = a1; bi = tid + 64; } else { bv = a0; bi = tid; }
            for (int off = 32; off > 0; off >>= 1) {
                float ov = __shfl_xor(bv, off);
                int   oi = __shfl_xor(bi, off);
                if (ov > bv || (ov == bv && oi < bi)) { bv = ov; bi = oi; }
            }
            if (tid == 0) { s_m = m; s_s = e; s_ind = bi; }
        }
        __syncthreads();
        int ind = s_ind;
        if (tid == 0) {
            if (!greedy) out[O0 + b * (NN - 1) + t] = logits[ind] - s_m - logf(s_s);
            dist += dis[b * NN * NN + last * NN + ind];
            if (greedy) out[O4 + b * NN * NN + last * NN + ind] = 1.0f;
        }
        last = ind;
        __syncthreads();
    }
    if (tid == 0) {
        if (!greedy) out[O1 + b] = dist;
        else         out[O2 + b] = dist;
    }
}

// ---------------- host launcher ----------------
extern "C" void kernel_launch(void* const* d_in, const int* in_sizes, int n_in,
                              void* d_out, int out_size, void* d_ws, size_t ws_size,
                              hipStream_t stream) {
    (void)in_sizes; (void)n_in; (void)out_size;
    const float* node   = (const float*)d_in[0];
    const float* demand = (const float*)d_in[1];
    const float* dis    = (const float*)d_in[2];
    const float* Wn0    = (const float*)d_in[3];
    const float* bn0    = (const float*)d_in[4];
    const float* Ws     = (const float*)d_in[5];
    const float* Wngh   = (const float*)d_in[6];
    const float* We     = (const float*)d_in[7];
    const float* be     = (const float*)d_in[8];
    const float* Wih    = (const float*)d_in[9];
    const float* Whh    = (const float*)d_in[10];
    const float* bih    = (const float*)d_in[11];
    const float* bhh    = (const float*)d_in[12];
    const float* Wq     = (const float*)d_in[13];
    const float* Wc     = (const float*)d_in[14];
    const float* bc     = (const float*)d_in[15];
    float* out = (float*)d_out;
    float* ws  = (float*)d_ws;

    float* hA  = ws;
    float* hB  = ws + 819200;
    float* hw  = ws + 1638400;      // hw during encoder; Z after
    float* A   = ws + 2457600;
    float* P0  = ws + 2457600;      // overlays A after encoder
    float* WqT = ws + 4915200;
    const size_t need_bytes = (size_t)4931584 * 4;
    const bool big_ws = ws_size >= need_bytes;

    hipLaunchKernelGGL(k_embed, dim3(3200), dim3(256), 0, stream, node, demand, Wn0, bn0, hA);
    hipLaunchKernelGGL(k_adj, dim3(6400), dim3(64), 0, stream, dis, A);

    float* cur = hA;
    float* nxt = hB;
    for (int l = 0; l < 3; l++) {
        hipLaunchKernelGGL(k_hw, dim3(800), dim3(256), 0, stream, cur, Wngh + l * 16384, hw);
        hipLaunchKernelGGL(k_agg, dim3(1600), dim3(256), 0, stream, cur, Ws + l * 16384, A, hw, nxt);
        float* tswap = cur; cur = nxt; nxt = tswap;
    }

    hipLaunchKernelGGL(k_predict, dim3(2500), dim3(256), 0, stream, dis, We, be, Wc, bc, out + O3);
    hipLaunchKernelGGL(k_zero, dim3(2500), dim3(256), 0, stream, out + O4, BB * NN * NN);

    if (big_ws) {
        hipLaunchKernelGGL(k_transpose128, dim3(64), dim3(256), 0, stream, Wq, WqT);
        hipLaunchKernelGGL(k_hw, dim3(800), dim3(256), 0, stream, cur, WqT, hw);   // Z
        hipLaunchKernelGGL(k_mm384, dim3(800, 3), dim3(256), 0, stream, cur, Wih, bih, P0);
        hipLaunchKernelGGL(k_decode3, dim3(64), dim3(768), 0, stream,
                           P0, hw, dis, Wih, Whh, bih, bhh, out);
    } else {
        // small-ws fallback: reuse decode2 path with in-place precompute impossible;
        // fall back to launching decode2 with P0/Z computed into the hw/A regions.
        hipLaunchKernelGGL(k_transpose128, dim3(64), dim3(256), 0, stream, Wq, WqT);
        hipLaunchKernelGGL(k_hw, dim3(800), dim3(256), 0, stream, cur, WqT, hw);
        hipLaunchKernelGGL(k_mm384, dim3(800, 3), dim3(256), 0, stream, cur, Wih, bih, P0);
        hipLaunchKernelGGL(k_decode2, dim3(128), dim3(768), 0, stream,
                           P0, hw, dis, Wih, Whh, bih, bhh, out);
    }
}

// Round 4
// 979.816 us; speedup vs baseline: 2.2950x; 2.2950x over previous
//
#include <hip/hip_runtime.h>
#include <math.h>

// Problem constants
#define BB 64
#define NN 100
#define HH 128
#define T3 384

// Output layout (floats, concatenated in return order)
#define O0 0            // sample_logprob [64,99]
#define O1 6336         // sample_distance [64,1]
#define O2 6400         // greedy_distance [64,1]
#define O3 6464         // predict_matrix [64,100,100,2]
#define O4 1286464      // greedy_solution_matrix [64,100,100]

#define TINYF 1.17549435e-38f
#define SCALEF 0.08838834764831845f

// ---------------- threefry2x32 (exact JAX implementation) ----------------
__device__ __forceinline__ unsigned rotl32(unsigned x, int d) {
    return (x << d) | (x >> (32 - d));
}

__device__ __forceinline__ void tf2x32(unsigned ks0, unsigned ks1,
                                       unsigned x0, unsigned x1,
                                       unsigned& o0, unsigned& o1) {
    unsigned ks2 = ks0 ^ ks1 ^ 0x1BD11BDAu;
    x0 += ks0; x1 += ks1;
    x0 += x1; x1 = rotl32(x1, 13); x1 ^= x0;
    x0 += x1; x1 = rotl32(x1, 15); x1 ^= x0;
    x0 += x1; x1 = rotl32(x1, 26); x1 ^= x0;
    x0 += x1; x1 = rotl32(x1, 6);  x1 ^= x0;
    x0 += ks1; x1 += ks2 + 1u;
    x0 += x1; x1 = rotl32(x1, 17); x1 ^= x0;
    x0 += x1; x1 = rotl32(x1, 29); x1 ^= x0;
    x0 += x1; x1 = rotl32(x1, 16); x1 ^= x0;
    x0 += x1; x1 = rotl32(x1, 24); x1 ^= x0;
    x0 += ks2; x1 += ks0 + 2u;
    x0 += x1; x1 = rotl32(x1, 13); x1 ^= x0;
    x0 += x1; x1 = rotl32(x1, 15); x1 ^= x0;
    x0 += x1; x1 = rotl32(x1, 26); x1 ^= x0;
    x0 += x1; x1 = rotl32(x1, 6);  x1 ^= x0;
    x0 += ks0; x1 += ks1 + 3u;
    x0 += x1; x1 = rotl32(x1, 17); x1 ^= x0;
    x0 += x1; x1 = rotl32(x1, 29); x1 ^= x0;
    x0 += x1; x1 = rotl32(x1, 16); x1 ^= x0;
    x0 += x1; x1 = rotl32(x1, 24); x1 ^= x0;
    x0 += ks1; x1 += ks2 + 4u;
    x0 += x1; x1 = rotl32(x1, 13); x1 ^= x0;
    x0 += x1; x1 = rotl32(x1, 15); x1 ^= x0;
    x0 += x1; x1 = rotl32(x1, 26); x1 ^= x0;
    x0 += x1; x1 = rotl32(x1, 6);  x1 ^= x0;
    x0 += ks2; x1 += ks0 + 5u;
    o0 = x0; o1 = x1;
}

__device__ __forceinline__ float gumbel_f(unsigned k0, unsigned k1, unsigned f) {
    unsigned o0, o1;
    tf2x32(k0, k1, 0u, f, o0, o1);
    unsigned bits = o0 ^ o1;
    float u01 = __uint_as_float((bits >> 9) | 0x3F800000u) - 1.0f;
    float u = fmaxf(TINYF, u01 * (1.0f - TINYF) + TINYF);
    return -logf(-logf(u));
}

// ---------------- encoder kernels ----------------

__global__ void k_embed(const float* __restrict__ node, const float* __restrict__ demand,
                        const float* __restrict__ Wn0, const float* __restrict__ bn0,
                        float* __restrict__ h) {
    int idx = blockIdx.x * 256 + threadIdx.x;
    if (idx >= BB * NN * HH) return;
    int r = idx >> 7, c = idx & 127;
    float v = node[r * 2] * Wn0[c] + node[r * 2 + 1] * Wn0[128 + c]
            + demand[r] * Wn0[256 + c] + bn0[c];
    h[idx] = fmaxf(v, 0.0f);
}

__global__ void k_adj(const float* __restrict__ dis, float* __restrict__ A) {
    int row = blockIdx.x;
    const float* d = dis + row * NN;
    int l = threadIdx.x;
    float v0 = (l < NN) ? -d[l] : -__builtin_inff();
    float v1 = (l + 64 < NN) ? -d[l + 64] : -__builtin_inff();
    float m = fmaxf(v0, v1);
    for (int off = 32; off > 0; off >>= 1) m = fmaxf(m, __shfl_xor(m, off));
    float e0 = (l < NN) ? expf(v0 - m) : 0.0f;
    float e1 = (l + 64 < NN) ? expf(v1 - m) : 0.0f;
    float s = e0 + e1;
    for (int off = 32; off > 0; off >>= 1) s += __shfl_xor(s, off);
    float inv = 1.0f / s;
    if (l < NN) A[row * NN + l] = e0 * inv;
    if (l + 64 < NN) A[row * NN + l + 64] = e1 * inv;
}

// out[6400x128] = h[6400x128] @ W[128x128]
__global__ void k_hw(const float* __restrict__ h, const float* __restrict__ W,
                     float* __restrict__ out) {
    __shared__ float hs[8 * 128];
    int block_row = blockIdx.x * 8;
    int tid = threadIdx.x;
    int col = tid & 127;
    int rg = tid >> 7;
    for (int i = tid; i < 8 * 128; i += 256) hs[i] = h[block_row * 128 + i];
    __syncthreads();
    float acc[4] = {0.f, 0.f, 0.f, 0.f};
    for (int k = 0; k < 128; k++) {
        float w = W[k * 128 + col];
#pragma unroll
        for (int r = 0; r < 4; r++) acc[r] += hs[(rg + 2 * r) * 128 + k] * w;
    }
#pragma unroll
    for (int r = 0; r < 4; r++)
        out[(block_row + rg + 2 * r) * 128 + col] = acc[r];
}

// out[6400x384] = h[6400x128] @ W[128x384] + bias[384]
__global__ void k_mm384(const float* __restrict__ h, const float* __restrict__ W,
                        const float* __restrict__ bias, float* __restrict__ out) {
    __shared__ float hs[8 * 128];
    int block_row = blockIdx.x * 8;
    int tid = threadIdx.x;
    int col = blockIdx.y * 128 + (tid & 127);
    int rg = tid >> 7;
    for (int i = tid; i < 8 * 128; i += 256) hs[i] = h[block_row * 128 + i];
    __syncthreads();
    float acc[4] = {0.f, 0.f, 0.f, 0.f};
    for (int k = 0; k < 128; k++) {
        float w = W[k * 384 + col];
#pragma unroll
        for (int r = 0; r < 4; r++) acc[r] += hs[(rg + 2 * r) * 128 + k] * w;
    }
    float b = bias[col];
#pragma unroll
    for (int r = 0; r < 4; r++)
        out[(block_row + rg + 2 * r) * 384 + col] = acc[r] + b;
}

__global__ void k_transpose128(const float* __restrict__ Wq, float* __restrict__ WqT) {
    int i = blockIdx.x * 256 + threadIdx.x;
    if (i >= 128 * 128) return;
    int k = i >> 7, c = i & 127;
    WqT[k * 128 + c] = Wq[c * 128 + k];
}

__global__ void k_agg(const float* __restrict__ h, const float* __restrict__ Ws,
                      const float* __restrict__ A, const float* __restrict__ hw,
                      float* __restrict__ out) {
    __shared__ float hs[4 * 128];
    __shared__ float As[4 * 100];
    int b = blockIdx.x / 25;
    int i0 = (blockIdx.x % 25) * 4;
    int tid = threadIdx.x;
    int col = tid & 127;
    int rg = tid >> 7;
    int rowbase = b * NN + i0;
    for (int idx = tid; idx < 4 * 128; idx += 256) hs[idx] = h[rowbase * 128 + idx];
    for (int idx = tid; idx < 4 * 100; idx += 256) As[idx] = A[rowbase * 100 + idx];
    __syncthreads();
    float acc0 = 0.f, acc1 = 0.f;
    for (int k = 0; k < 128; k++) {
        float w = Ws[k * 128 + col];
        acc0 += hs[rg * 128 + k] * w;
        acc1 += hs[(rg + 2) * 128 + k] * w;
    }
    const float* hwb = hw + b * NN * 128;
    for (int j = 0; j < NN; j++) {
        float v = hwb[j * 128 + col];
        acc0 += As[rg * 100 + j] * v;
        acc1 += As[(rg + 2) * 100 + j] * v;
    }
    out[(rowbase + rg) * 128 + col]     = fmaxf(acc0, 0.0f);
    out[(rowbase + rg + 2) * 128 + col] = fmaxf(acc1, 0.0f);
}

__global__ void k_predict(const float* __restrict__ dis, const float* __restrict__ We,
                          const float* __restrict__ be, const float* __restrict__ Wc,
                          const float* __restrict__ bc, float* __restrict__ out3) {
    __shared__ float sWe[128], sbe[128], sc0[128], sc1[128];
    int tid = threadIdx.x;
    if (tid < 128) {
        sWe[tid] = We[tid];
        sbe[tid] = be[tid];
        sc0[tid] = Wc[tid * 2];
        sc1[tid] = Wc[tid * 2 + 1];
    }
    __syncthreads();
    float b0 = bc[0], b1 = bc[1];
    for (int pos = blockIdx.x * 256 + tid; pos < BB * NN * NN; pos += gridDim.x * 256) {
        float d = dis[pos];
        float a0 = b0, a1 = b1;
        for (int k = 0; k < 128; k++) {
            float e = fmaxf(d * sWe[k] + sbe[k], 0.0f);
            a0 += e * sc0[k];
            a1 += e * sc1[k];
        }
        float m = fmaxf(a0, a1);
        float p0 = expf(a0 - m), p1 = expf(a1 - m);
        float inv = 1.0f / (p0 + p1);
        out3[pos * 2]     = p0 * inv;
        out3[pos * 2 + 1] = p1 * inv;
    }
}

__global__ void k_zero(float* __restrict__ p, int n) {
    int i = blockIdx.x * 256 + threadIdx.x;
    if (i < n) p[i] = 0.0f;
}

// ---------------- decoder v4: 64 blocks x 512 thr, fused modes, spill-proof tiles ----------
// matvec tile: 4 j-columns x k-window, both modes. h read as wave-uniform float4
// broadcasts from LDS (conflict-free). ~32 VGPRs live — no scratch.
__device__ __forceinline__ void matvec_tile4(const float* __restrict__ W,   // &W[k0*384 + j0]
                                             const float* __restrict__ hp,  // &h[k0]; modes at +0, +132
                                             int nk4,
                                             float* __restrict__ pg0,       // partial out, mode 0 (float4-aligned)
                                             float* __restrict__ pg1) {
    float a00 = 0.f, a01 = 0.f, a02 = 0.f, a03 = 0.f;
    float a10 = 0.f, a11 = 0.f, a12 = 0.f, a13 = 0.f;
#pragma unroll 4
    for (int k4 = 0; k4 < nk4; ++k4) {
        float4 hA = *(const float4*)(hp + 4 * k4);
        float4 hB = *(const float4*)(hp + 132 + 4 * k4);
        const float* Wk = W + (size_t)(4 * k4) * T3;
        float4 w0 = *(const float4*)(Wk);
        float4 w1 = *(const float4*)(Wk + T3);
        float4 w2 = *(const float4*)(Wk + 2 * T3);
        float4 w3 = *(const float4*)(Wk + 3 * T3);
        a00 += hA.x * w0.x; a01 += hA.x * w0.y; a02 += hA.x * w0.z; a03 += hA.x * w0.w;
        a10 += hB.x * w0.x; a11 += hB.x * w0.y; a12 += hB.x * w0.z; a13 += hB.x * w0.w;
        a00 += hA.y * w1.x; a01 += hA.y * w1.y; a02 += hA.y * w1.z; a03 += hA.y * w1.w;
        a10 += hB.y * w1.x; a11 += hB.y * w1.y; a12 += hB.y * w1.z; a13 += hB.y * w1.w;
        a00 += hA.z * w2.x; a01 += hA.z * w2.y; a02 += hA.z * w2.z; a03 += hA.z * w2.w;
        a10 += hB.z * w2.x; a11 += hB.z * w2.y; a12 += hB.z * w2.z; a13 += hB.z * w2.w;
        a00 += hA.w * w3.x; a01 += hA.w * w3.y; a02 += hA.w * w3.z; a03 += hA.w * w3.w;
        a10 += hB.w * w3.x; a11 += hB.w * w3.y; a12 += hB.w * w3.z; a13 += hB.w * w3.w;
    }
    float4 o;
    o.x = a00; o.y = a01; o.z = a02; o.w = a03;
    *(float4*)pg0 = o;
    o.x = a10; o.y = a11; o.z = a12; o.w = a13;
    *(float4*)pg1 = o;
}

__global__ __launch_bounds__(512, 2) void k_decode4(
    const float* __restrict__ P0,       // [6400, 384]  x@Wih0 + bih0
    const float* __restrict__ Z,        // [6400, 128]  x@Wq^T
    const float* __restrict__ dis,
    const float* __restrict__ Wih,      // [2,128,384]
    const float* __restrict__ Whh,      // [2,128,384]
    const float* __restrict__ bih,
    const float* __restrict__ bhh,
    float* __restrict__ out) {
    __shared__ float Zs[NN * 132];          // 52.8 KB
    __shared__ float h0s[2 * 132], h1s[2 * 132];
    __shared__ float gi0s[2 * 384];
    __shared__ float pgA[2 * 2 * 392];      // gh0 partials [ks2][m2][392]
    __shared__ float pgB[2 * 2 * 392];      // gh1 partials
    __shared__ float pgC[4 * 2 * 392];      // gi1 partials [ks4][m2][392]
    __shared__ float sbhh0[T3], sbih1[T3], sbhh1[T3];
    __shared__ float pl[2 * 2 * 100];       // [m][ks][n]
    __shared__ float gum[128];
    __shared__ int s_ind2[2];

    const int tid = threadIdx.x;
    const int b = blockIdx.x;

    const float* __restrict__ Wih1 = Wih + 128 * T3;

    // ---- static staging ----
    for (int i4 = tid; i4 < NN * 32; i4 += 512) {
        int r = i4 >> 5, c4 = (i4 & 31) * 4;
        *(float4*)&Zs[r * 132 + c4] = *(const float4*)&Z[(b * NN + r) * 128 + c4];
    }
    if (tid < T3) {
        sbhh0[tid] = bhh[tid];
        sbih1[tid] = bih[T3 + tid];
        sbhh1[tid] = bhh[T3 + tid];
    }
    if (tid < 256) {
        int m = tid >> 7, i = tid & 127;
        h0s[m * 132 + i] = 0.0f;
        h1s[m * 132 + i] = 0.0f;
    }
    if (tid == 0) { s_ind2[0] = 0; s_ind2[1] = 0; }

    unsigned kk0, kk1;
    tf2x32(0u, 42u, 0u, 0u, kk0, kk1);   // k1 of split(key(42))

    int lastm = 0;       // meaningful in tid<128 (selection threads)
    float dist = 0.0f;
    __syncthreads();

    for (int t = 0; t < NN - 1; t++) {
        // ===== phase A: gh0 & gh1 partials (384 thr); aux 128 thr: gi0 prefetch + RNG =====
        if (tid < 384) {
            const int unit = tid / 192;              // 0: Whh0*h0, 1: Whh1*h1
            const int r = tid - unit * 192;
            const int ks = r / 96, j4 = r - ks * 96;
            const int j0 = j4 * 4, k0 = ks * 64;
            const float* W = Whh + unit * (128 * T3) + (size_t)k0 * T3 + j0;
            const float* hp = ((unit == 0) ? h0s : h1s) + k0;
            float* pg = (unit == 0) ? pgA : pgB;
            matvec_tile4(W, hp, 16,
                         &pg[(ks * 2 + 0) * 392 + j0],
                         &pg[(ks * 2 + 1) * 392 + j0]);
        } else {
            int u = tid - 384;                       // 0..127
            int l0 = s_ind2[0], l1 = s_ind2[1];
#pragma unroll
            for (int q = 0; q < 6; q++) {
                int f = u + 128 * q;
                int m = (f >= 384) ? 1 : 0;
                int j = f - m * 384;
                gi0s[f] = P0[(size_t)(b * NN + (m ? l1 : l0)) * T3 + j];
            }
            // RNG: advance chain, fill gumbel table
            unsigned sk0, sk1, nk0, nk1;
            tf2x32(kk0, kk1, 0u, 1u, sk0, sk1);
            tf2x32(kk0, kk1, 0u, 0u, nk0, nk1);
            kk0 = nk0; kk1 = nk1;
            if (u < NN) gum[u] = gumbel_f(sk0, sk1, (unsigned)(b * NN + u));
        }
        __syncthreads();

        // ===== phase B: h0 update (256 thr) =====
        if (tid < 256) {
            int m = tid >> 7, i = tid & 127;
            float ghr = pgA[(0 * 2 + m) * 392 + i]       + pgA[(1 * 2 + m) * 392 + i]       + sbhh0[i];
            float ghz = pgA[(0 * 2 + m) * 392 + i + 128] + pgA[(1 * 2 + m) * 392 + i + 128] + sbhh0[i + 128];
            float ghn = pgA[(0 * 2 + m) * 392 + i + 256] + pgA[(1 * 2 + m) * 392 + i + 256] + sbhh0[i + 256];
            float rr = 1.0f / (1.0f + expf(-(gi0s[m * 384 + i] + ghr)));
            float zz = 1.0f / (1.0f + expf(-(gi0s[m * 384 + i + 128] + ghz)));
            float nn = tanhf(gi0s[m * 384 + i + 256] + rr * ghn);
            h0s[m * 132 + i] = (1.0f - zz) * nn + zz * h0s[m * 132 + i];
        }
        __syncthreads();

        // ===== phase C: gi1 partials (384 thr, k-split 4) =====
        if (tid < 384) {
            const int ks = tid / 96, j4 = tid - ks * 96;
            const int j0 = j4 * 4, k0 = ks * 32;
            const float* W = Wih1 + (size_t)k0 * T3 + j0;
            matvec_tile4(W, h0s + k0, 8,
                         &pgC[(ks * 2 + 0) * 392 + j0],
                         &pgC[(ks * 2 + 1) * 392 + j0]);
        }
        __syncthreads();

        // ===== phase D: h1 update (256 thr) =====
        if (tid < 256) {
            int m = tid >> 7, i = tid & 127;
            float gir = sbih1[i], giz = sbih1[i + 128], gin = sbih1[i + 256];
#pragma unroll
            for (int ks = 0; ks < 4; ks++) {
                int pb = (ks * 2 + m) * 392;
                gir += pgC[pb + i];
                giz += pgC[pb + i + 128];
                gin += pgC[pb + i + 256];
            }
            float ghr = pgB[(0 * 2 + m) * 392 + i]       + pgB[(1 * 2 + m) * 392 + i]       + sbhh1[i];
            float ghz = pgB[(0 * 2 + m) * 392 + i + 128] + pgB[(1 * 2 + m) * 392 + i + 128] + sbhh1[i + 128];
            float ghn = pgB[(0 * 2 + m) * 392 + i + 256] + pgB[(1 * 2 + m) * 392 + i + 256] + sbhh1[i + 256];
            float rr = 1.0f / (1.0f + expf(-(gir + ghr)));
            float zz = 1.0f / (1.0f + expf(-(giz + ghz)));
            float nn = tanhf(gin + rr * ghn);
            h1s[m * 132 + i] = (1.0f - zz) * nn + zz * h1s[m * 132 + i];
        }
        __syncthreads();

        // ===== phase E: logits partials (200 thr: n x ks2, both modes) =====
        if (tid < 200) {
            int ks = tid / 100, n = tid - ks * 100;
            int k0 = ks * 64;
            const float* Zp = &Zs[n * 132 + k0];
            const float* hp = &h1s[k0];
            float a0 = 0.f, a1 = 0.f;
#pragma unroll 4
            for (int q = 0; q < 16; q++) {
                float4 z4 = *(const float4*)(Zp + 4 * q);
                float4 hA = *(const float4*)(hp + 4 * q);
                float4 hB = *(const float4*)(hp + 132 + 4 * q);
                a0 += hA.x * z4.x; a0 += hA.y * z4.y; a0 += hA.z * z4.z; a0 += hA.w * z4.w;
                a1 += hB.x * z4.x; a1 += hB.y * z4.y; a1 += hB.z * z4.z; a1 += hB.w * z4.w;
            }
            pl[(0 * 2 + ks) * 100 + n] = a0;
            pl[(1 * 2 + ks) * 100 + n] = a1;
        }
        __syncthreads();

        // ===== phase F: softmax stats + selection (wave0: sample, wave1: greedy) =====
        if (tid < 128) {
            const int m = tid >> 6, lane = tid & 63;
            float v0, v1 = -__builtin_inff();
            v0 = (pl[(m * 2 + 0) * 100 + lane] + pl[(m * 2 + 1) * 100 + lane]) * SCALEF;
            if (lane + 64 < NN)
                v1 = (pl[(m * 2 + 0) * 100 + lane + 64] + pl[(m * 2 + 1) * 100 + lane + 64]) * SCALEF;
            float mx = fmaxf(v0, v1);
            for (int off = 32; off > 0; off >>= 1) mx = fmaxf(mx, __shfl_xor(mx, off));
            float e = expf(v0 - mx) + ((lane + 64 < NN) ? expf(v1 - mx) : 0.0f);
            for (int off = 32; off > 0; off >>= 1) e += __shfl_xor(e, off);
            float a0 = v0, a1 = v1;
            if (m == 0) {
                a0 += gum[lane];
                if (lane + 64 < NN) a1 += gum[lane + 64];
            }
            float bv; int bi;
            if (a1 > a0) { bv = a1; bi = lane + 64; } else { bv = a0; bi = lane; }
            for (int off = 32; off > 0; off >>= 1) {
                float ov = __shfl_xor(bv, off);
                int   oi = __shfl_xor(bi, off);
                if (ov > bv || (ov == bv && oi < bi)) { bv = ov; bi = oi; }
            }
            int ind = bi;
            float la = __shfl(v0, ind & 63);
            float lb = __shfl(v1, ind & 63);
            float lv = (ind < 64) ? la : lb;
            if (lane == 0) {
                if (m == 0) out[O0 + b * (NN - 1) + t] = lv - mx - logf(e);
                else        out[O4 + (size_t)b * NN * NN + lastm * NN + ind] = 1.0f;
                s_ind2[m] = ind;
            }
            dist += dis[b * NN * NN + lastm * NN + ind];
            lastm = ind;
        }
        __syncthreads();
    }

    if (tid == 0)  out[O1 + b] = dist;
    if (tid == 64) out[O2 + b] = dist;
}

// ---------------- fallback decoder (round-2 verified, small ws) ----------------
__global__ __launch_bounds__(768) void k_decode2(
    const float* __restrict__ P0, const float* __restrict__ Z,
    const float* __restrict__ dis,
    const float* __restrict__ Wih, const float* __restrict__ Whh,
    const float* __restrict__ bih, const float* __restrict__ bhh,
    float* __restrict__ out) {
    __shared__ float Zs[NN * 129];
    __shared__ float h0s[128], h1s[128];
    __shared__ float gi0s[T3];
    __shared__ float pg0[2 * T3];
    __shared__ float gi1s[T3], gh1s[T3];
    __shared__ float sbhh0[T3], sbih1[T3], sbhh1[T3];
    __shared__ float plx[4 * NN];
    __shared__ float logits[NN];
    __shared__ float s_m, s_s;
    __shared__ int s_ind;

    const int tid = threadIdx.x;
    const int b = blockIdx.x >> 1;
    const int greedy = blockIdx.x & 1;

    const float* Whh0 = Whh;
    const float* Wih1 = Wih + 128 * T3;
    const float* Whh1 = Whh + 128 * T3;

    for (int idx = tid; idx < NN * 128; idx += 768) {
        int r = idx >> 7, c = idx & 127;
        Zs[r * 129 + c] = Z[(b * NN + r) * 128 + c];
    }
    if (tid < T3) {
        sbhh0[tid] = bhh[tid];
        sbih1[tid] = bih[T3 + tid];
        sbhh1[tid] = bhh[T3 + tid];
    }
    if (tid < 128) { h0s[tid] = 0.0f; h1s[tid] = 0.0f; }

    unsigned kk0, kk1;
    tf2x32(0u, 42u, 0u, 0u, kk0, kk1);

    int last = 0;
    float dist = 0.0f;
    __syncthreads();

    for (int t = 0; t < NN - 1; t++) {
        unsigned sk0, sk1, nk0, nk1;
        tf2x32(kk0, kk1, 0u, 1u, sk0, sk1);
        tf2x32(kk0, kk1, 0u, 0u, nk0, nk1);
        kk0 = nk0; kk1 = nk1;

        {
            const float* P0row = P0 + (size_t)(b * NN + last) * T3;
            if (tid < T3) {
                int j = tid;
                float acc = 0.0f;
                for (int k = 0; k < 64; k++) acc += h0s[k] * Whh0[k * T3 + j];
                pg0[j] = acc;
                gi0s[j] = P0row[j];
            } else {
                int j = tid - T3;
                float acc = 0.0f;
                for (int k = 64; k < 128; k++) acc += h0s[k] * Whh0[k * T3 + j];
                pg0[T3 + j] = acc;
            }
        }
        __syncthreads();
        if (tid < 128) {
            float ghr = pg0[tid] + pg0[T3 + tid] + sbhh0[tid];
            float ghz = pg0[tid + 128] + pg0[T3 + tid + 128] + sbhh0[tid + 128];
            float ghn = pg0[tid + 256] + pg0[T3 + tid + 256] + sbhh0[tid + 256];
            float r = 1.0f / (1.0f + expf(-(gi0s[tid] + ghr)));
            float z = 1.0f / (1.0f + expf(-(gi0s[tid + 128] + ghz)));
            float n = tanhf(gi0s[tid + 256] + r * ghn);
            h0s[tid] = (1.0f - z) * n + z * h0s[tid];
        }
        __syncthreads();
        if (tid < T3) {
            int j = tid;
            float acc = sbih1[j];
            for (int k = 0; k < 128; k++) acc += h0s[k] * Wih1[k * T3 + j];
            gi1s[j] = acc;
        } else {
            int j = tid - T3;
            float acc = sbhh1[j];
            for (int k = 0; k < 128; k++) acc += h1s[k] * Whh1[k * T3 + j];
            gh1s[j] = acc;
        }
        __syncthreads();
        if (tid < 128) {
            float r = 1.0f / (1.0f + expf(-(gi1s[tid] + gh1s[tid])));
            float z = 1.0f / (1.0f + expf(-(gi1s[tid + 128] + gh1s[tid + 128])));
            float n = tanhf(gi1s[tid + 256] + r * gh1s[tid + 256]);
            h1s[tid] = (1.0f - z) * n + z * h1s[tid];
        }
        __syncthreads();
        if (tid < 400) {
            int n = tid % 100, p = tid / 100;
            int k0 = p * 32;
            float acc = 0.0f;
            for (int kk = 0; kk < 32; kk++) acc += h1s[k0 + kk] * Zs[n * 129 + k0 + kk];
            plx[p * 100 + n] = acc;
        }
        __syncthreads();
        if (tid < 64) {
            float v0 = -__builtin_inff(), v1 = -__builtin_inff();
            {
                int n = tid;
                v0 = (plx[n] + plx[100 + n] + plx[200 + n] + plx[300 + n]) * SCALEF;
                logits[n] = v0;
            }
            if (tid + 64 < NN) {
                int n = tid + 64;
                v1 = (plx[n] + plx[100 + n] + plx[200 + n] + plx[300 + n]) * SCALEF;
                logits[n] = v1;
            }
            float m = fmaxf(v0, v1);
            for (int off = 32; off > 0; off >>= 1) m = fmaxf(m, __shfl_xor(m, off));
            float e = expf(v0 - m) + ((tid + 64 < NN) ? expf(v1 - m) : 0.0f);
            for (int off = 32; off > 0; off >>= 1) e += __shfl_xor(e, off);
            float a0 = v0, a1 = v1;
            if (!greedy) {
                a0 = v0 + gumbel_f(sk0, sk1, (unsigned)(b * NN + tid));
                if (tid + 64 < NN) a1 = v1 + gumbel_f(sk0, sk1, (unsigned)(b * NN + tid + 64));
            }
            float bv; int bi;
            if (a1 > a0) { bv = a1; bi = tid + 64; } else { bv = a0; bi = tid; }
            for (int off = 32; off > 0; off >>= 1) {
                float ov = __shfl_xor(bv, off);
                int   oi = __shfl_xor(bi, off);
                if (ov > bv || (ov == bv && oi < bi)) { bv = ov; bi = oi; }
            }
            if (tid == 0) { s_m = m; s_s = e; s_ind = bi; }
        }
        __syncthreads();
        int ind = s_ind;
        if (tid == 0) {
            if (!greedy) out[O0 + b * (NN - 1) + t] = logits[ind] - s_m - logf(s_s);
            dist += dis[b * NN * NN + last * NN + ind];
            if (greedy) out[O4 + b * NN * NN + last * NN + ind] = 1.0f;
        }
        last = ind;
        __syncthreads();
    }
    if (tid == 0) {
        if (!greedy) out[O1 + b] = dist;
        else         out[O2 + b] = dist;
    }
}

// ---------------- host launcher ----------------
extern "C" void kernel_launch(void* const* d_in, const int* in_sizes, int n_in,
                              void* d_out, int out_size, void* d_ws, size_t ws_size,
                              hipStream_t stream) {
    (void)in_sizes; (void)n_in; (void)out_size;
    const float* node   = (const float*)d_in[0];
    const float* demand = (const float*)d_in[1];
    const float* dis    = (const float*)d_in[2];
    const float* Wn0    = (const float*)d_in[3];
    const float* bn0    = (const float*)d_in[4];
    const float* Ws     = (const float*)d_in[5];
    const float* Wngh   = (const float*)d_in[6];
    const float* We     = (const float*)d_in[7];
    const float* be     = (const float*)d_in[8];
    const float* Wih    = (const float*)d_in[9];
    const float* Whh    = (const float*)d_in[10];
    const float* bih    = (const float*)d_in[11];
    const float* bhh    = (const float*)d_in[12];
    const float* Wq     = (const float*)d_in[13];
    const float* Wc     = (const float*)d_in[14];
    const float* bc     = (const float*)d_in[15];
    float* out = (float*)d_out;
    float* ws  = (float*)d_ws;

    float* hA  = ws;
    float* hB  = ws + 819200;
    float* hw  = ws + 1638400;      // hw during encoder; Z after
    float* A   = ws + 2457600;
    float* P0  = ws + 2457600;      // overlays A after encoder
    float* WqT = ws + 4915200;
    const size_t need_bytes = (size_t)4931584 * 4;
    const bool big_ws = ws_size >= need_bytes;

    hipLaunchKernelGGL(k_embed, dim3(3200), dim3(256), 0, stream, node, demand, Wn0, bn0, hA);
    hipLaunchKernelGGL(k_adj, dim3(6400), dim3(64), 0, stream, dis, A);

    float* cur = hA;
    float* nxt = hB;
    for (int l = 0; l < 3; l++) {
        hipLaunchKernelGGL(k_hw, dim3(800), dim3(256), 0, stream, cur, Wngh + l * 16384, hw);
        hipLaunchKernelGGL(k_agg, dim3(1600), dim3(256), 0, stream, cur, Ws + l * 16384, A, hw, nxt);
        float* tswap = cur; cur = nxt; nxt = tswap;
    }

    hipLaunchKernelGGL(k_predict, dim3(2500), dim3(256), 0, stream, dis, We, be, Wc, bc, out + O3);
    hipLaunchKernelGGL(k_zero, dim3(2500), dim3(256), 0, stream, out + O4, BB * NN * NN);

    hipLaunchKernelGGL(k_transpose128, dim3(64), dim3(256), 0, stream, Wq, WqT);
    hipLaunchKernelGGL(k_hw, dim3(800), dim3(256), 0, stream, cur, WqT, hw);   // Z
    hipLaunchKernelGGL(k_mm384, dim3(800, 3), dim3(256), 0, stream, cur, Wih, bih, P0);
    if (big_ws) {
        hipLaunchKernelGGL(k_decode4, dim3(64), dim3(512), 0, stream,
                           P0, hw, dis, Wih, Whh, bih, bhh, out);
    } else {
        hipLaunchKernelGGL(k_decode2, dim3(128), dim3(768), 0, stream,
                           P0, hw, dis, Wih, Whh, bih, bhh, out);
    }
}